// Round 2
// 878.642 us; speedup vs baseline: 1.1775x; 1.1775x over previous
//
#include <hip/hip_runtime.h>
#include <math.h>

#define BB 8
#define NN 2000
#define FIN 128
#define HH 4
#define FO 64
#define CC 256  // HH*FO

typedef short bf16x8 __attribute__((ext_vector_type(8)));
typedef float f32x4 __attribute__((ext_vector_type(4)));
typedef unsigned long long u64;

__device__ __forceinline__ unsigned short f2bf(float v) {
    union { float f; unsigned u; } x;
    x.f = v;
    unsigned r = x.u + 0x7fffu + ((x.u >> 16) & 1u);  // RNE
    return (unsigned short)(r >> 16);
}

// ---------------------------------------------------------------------------
// K1: h = x @ W.  rows = B*N = 16000, K = 128, cols = 256.
// ---------------------------------------------------------------------------
__global__ __launch_bounds__(256) void k_gemm_xw(const float* __restrict__ x,
                                                 const float* __restrict__ W,
                                                 float* __restrict__ hfeat) {
    __shared__ float xs[16 * FIN];
    const int row0 = blockIdx.x * 16;
    const int t = threadIdx.x;
    for (int k = t; k < 16 * FIN; k += 256) xs[k] = x[row0 * FIN + k];
    __syncthreads();
    const int c = t;
    float acc[16];
#pragma unroll
    for (int r = 0; r < 16; ++r) acc[r] = 0.f;
#pragma unroll 2
    for (int k = 0; k < FIN; k += 4) {
        const float w0 = W[(k + 0) * CC + c];
        const float w1 = W[(k + 1) * CC + c];
        const float w2 = W[(k + 2) * CC + c];
        const float w3 = W[(k + 3) * CC + c];
#pragma unroll
        for (int r = 0; r < 16; ++r) {
            const float4 xv = *(const float4*)(xs + r * FIN + k);
            acc[r] = fmaf(xv.x, w0, fmaf(xv.y, w1, fmaf(xv.z, w2, fmaf(xv.w, w3, acc[r]))));
        }
    }
#pragma unroll
    for (int r = 0; r < 16; ++r) hfeat[(row0 + r) * CC + c] = acc[r];
}

// ---------------------------------------------------------------------------
// K1b: adjacency bitmask.  adjb[i][w] bit l = (adj[i][w*64+l] != 0).
// Rows padded to 2048 bits (32 u64 words); pad bits are 0.
// One wave per word.  16 MB int32 -> 512 KB (L2-resident everywhere).
// NOTE: adjb lives in the alpha scratch region -> must NOT be read by
// k_alpha (which overwrites alpha).  k_alpha reads the original adj input.
// ---------------------------------------------------------------------------
__global__ __launch_bounds__(256) void k_adjbits(const int* __restrict__ adj,
                                                 u64* __restrict__ adjb) {
    const int w = blockIdx.x * 4 + (threadIdx.x >> 6);  // [0, 64000)
    const int lane = threadIdx.x & 63;
    const int i = w >> 5, wd = w & 31;
    const int j = wd * 64 + lane;
    int av = 0;
    if (j < NN) av = adj[(size_t)i * NN + j];
    const u64 mask = __ballot(av != 0);
    if (lane == 0) adjb[(size_t)i * 32 + wd] = mask;
}

// ---------------------------------------------------------------------------
// K2: e_src[b][h][n] = h·a_src, e_dst = h·a_dst.  Wave per (b,n,h).
// ---------------------------------------------------------------------------
__global__ __launch_bounds__(256) void k_calc_e(const float* __restrict__ hfeat,
                                                const float* __restrict__ a,
                                                float* __restrict__ e_src,
                                                float* __restrict__ e_dst) {
    const int widx = blockIdx.x * 4 + (threadIdx.x >> 6);
    const int lane = threadIdx.x & 63;
    const int b = widx / (NN * HH);
    const int rem = widx - b * (NN * HH);
    const int n = rem / HH;
    const int h = rem - n * HH;
    const float hv = hfeat[((b * NN + n) * HH + h) * FO + lane];
    float p1 = hv * a[h * 2 * FO + lane];
    float p2 = hv * a[h * 2 * FO + FO + lane];
#pragma unroll
    for (int off = 32; off > 0; off >>= 1) {
        p1 += __shfl_xor(p1, off);
        p2 += __shfl_xor(p2, off);
    }
    if (lane == 0) {
        e_src[(b * HH + h) * NN + n] = p1;
        e_dst[(b * HH + h) * NN + n] = p2;
    }
}

// ---------------------------------------------------------------------------
// K3: softmax stats via bitmask (uniform u64 per wave-iteration instead of a
// per-lane int32 load: adj traffic 512 MB -> 16 MB).
// ---------------------------------------------------------------------------
__global__ __launch_bounds__(256) void k_softmax_ml(const u64* __restrict__ adjb,
                                                    const float* __restrict__ e_src,
                                                    const float* __restrict__ e_dst,
                                                    float* __restrict__ mArr,
                                                    float* __restrict__ rlArr) {
    const int widx = blockIdx.x * 4 + (threadIdx.x >> 6);  // [0, B*N*H)
    const int lane = threadIdx.x & 63;
    const int b = widx / (NN * HH);
    const int rem = widx - b * (NN * HH);
    const int i = rem / HH;
    const int h = rem - i * HH;
    const float* ed = e_dst + (b * HH + h) * NN;
    const u64* ab = adjb + (size_t)i * 32;
    const float ei = e_src[(b * HH + h) * NN + i];
    float m = -1e30f, l = 0.f;
    for (int j = lane; j < NN; j += 64) {
        const u64 wbits = ab[j >> 6];
        const unsigned hw = (unsigned)(wbits >> (lane & 32));
        const int bit = (hw >> (lane & 31)) & 1;
        float s = ei + ed[j];
        s = s > 0.f ? s : 0.2f * s;
        s = bit ? s : -1e30f;
        const float nm = fmaxf(m, s);
        l = l * __expf(m - nm) + __expf(s - nm);
        m = nm;
    }
#pragma unroll
    for (int off = 32; off > 0; off >>= 1) {
        const float mo = __shfl_xor(m, off);
        const float lo = __shfl_xor(l, off);
        const float mn = fmaxf(m, mo);
        l = l * __expf(m - mn) + lo * __expf(mo - mn);
        m = mn;
    }
    if (lane == 0) {
        mArr[(b * HH + h) * NN + i] = m;
        rlArr[(b * HH + h) * NN + i] = 1.f / l;
    }
}

// ---------------------------------------------------------------------------
// K3b: hT[b][h][f][j] = bf16(hfeat[b,j,h,f]), j padded to 2048 with zeros.
// LDS tile transpose, pitch 65 ushorts -> both directions <=2-way conflicts.
// 8.4 MB total, L2-resident; makes MFMA A-fragments direct 16B global loads.
// ---------------------------------------------------------------------------
__global__ __launch_bounds__(256) void k_transpose(const float* __restrict__ hfeat,
                                                   unsigned short* __restrict__ hT) {
    __shared__ unsigned short sm[64 * 65];
    const int jt = blockIdx.x, h = blockIdx.y, b = blockIdx.z;
    const int j0 = jt * 64;
    const int t = threadIdx.x;
    for (int k = t; k < 4096; k += 256) {
        const int jj = k >> 6, f = k & 63;
        const int j = j0 + jj;
        const float v = (j < NN) ? hfeat[((b * NN + j) * HH + h) * FO + f] : 0.f;
        sm[jj * 65 + f] = f2bf(v);
    }
    __syncthreads();
    unsigned short* dst = hT + ((size_t)(b * HH + h) * 64) * 2048 + j0;
    for (int k = t; k < 4096; k += 256) {
        const int f = k >> 6, jj = k & 63;
        dst[(size_t)f * 2048 + jj] = sm[jj * 65 + f];
    }
}

// ---------------------------------------------------------------------------
// K5: out partials, fully register-resident MFMA.  One INDEPENDENT wave per
// (b, h, 16-row i-tile): 4000 waves, no LDS, no barriers.
//   B-fragment (P): lane n=l16 <-> i = i0+l16; k = kk*32+quad*8+e -> computed
//     in-register from e_dst/bitmask (exp once per alpha element, as before).
//   A-fragment (Ht): lane m=l16 <-> f-row of hT; 8 consecutive j = one
//     global_load_dwordx4 from the bf16-transposed hT (L1/L2 broadcast:
//     all 4 waves of a block read identical addresses).
//   C/D: row(m)=quad*4+r = f offset -> acc[ft] is 4 consecutive f: direct
//     float4 store, no epilogue transpose.
// ---------------------------------------------------------------------------
__global__ __launch_bounds__(256) void k_out_mfma2(const u64* __restrict__ adjb,
                                                   const unsigned short* __restrict__ hT,
                                                   const float* __restrict__ e_src,
                                                   const float* __restrict__ e_dst,
                                                   const float* __restrict__ mArr,
                                                   const float* __restrict__ rlArr,
                                                   float* __restrict__ part) {
    const int w = blockIdx.x * 4 + (threadIdx.x >> 6);  // [0, 4000)
    const int lane = threadIdx.x & 63;
    const int b = w / 500;
    const int rem = w - b * 500;
    const int h = rem / 125;
    const int it = rem - h * 125;
    const int l16 = lane & 15, quad = lane >> 4;
    const int i = it * 16 + l16;  // < 2000 always (125*16 == 2000)
    const int bh = b * HH + h;
    const float es = e_src[bh * NN + i];
    const float mm = mArr[bh * NN + i];
    const float rl = rlArr[bh * NN + i];
    const float* ed = e_dst + bh * NN;
    const u64* ab = adjb + (size_t)i * 32;
    const unsigned short* hrow = hT + ((size_t)bh * 64 + l16) * 2048 + quad * 8;

    f32x4 acc[4];
#pragma unroll
    for (int ft = 0; ft < 4; ++ft) {
        acc[ft][0] = 0.f; acc[ft][1] = 0.f; acc[ft][2] = 0.f; acc[ft][3] = 0.f;
    }

    for (int jt = 0; jt < 32; ++jt) {
        const int j0 = jt * 64;
        const u64 bits = ab[jt];
        const unsigned m0 = ((unsigned)(bits >> (quad * 8))) & 0xffu;
        const unsigned m1 = ((unsigned)(bits >> 32) >> (quad * 8)) & 0xffu;
        // e_dst for this lane's 2x8 j values (16-lane broadcast within quad)
        const float4 ea0 = *(const float4*)(ed + j0 + quad * 8);
        const float4 ea1 = *(const float4*)(ed + j0 + quad * 8 + 4);
        const float4 eb0 = *(const float4*)(ed + j0 + 32 + quad * 8);
        const float4 eb1 = *(const float4*)(ed + j0 + 32 + quad * 8 + 4);
        const unsigned short* hp = hrow + j0;

        {   // kk = 0
            const float ev[8] = {ea0.x, ea0.y, ea0.z, ea0.w, ea1.x, ea1.y, ea1.z, ea1.w};
            bf16x8 bfr;
#pragma unroll
            for (int e = 0; e < 8; ++e) {
                float s = es + ev[e];
                s = s > 0.f ? s : 0.2f * s;
                float p = __expf(s - mm) * rl;
                p = ((m0 >> e) & 1u) ? p : 0.f;
                bfr[e] = (short)f2bf(p);
            }
#pragma unroll
            for (int ft = 0; ft < 4; ++ft) {
                const bf16x8 af = *(const bf16x8*)(hp + ft * 16 * 2048);
                acc[ft] = __builtin_amdgcn_mfma_f32_16x16x32_bf16(af, bfr, acc[ft], 0, 0, 0);
            }
        }
        {   // kk = 1
            const float ev[8] = {eb0.x, eb0.y, eb0.z, eb0.w, eb1.x, eb1.y, eb1.z, eb1.w};
            bf16x8 bfr;
#pragma unroll
            for (int e = 0; e < 8; ++e) {
                float s = es + ev[e];
                s = s > 0.f ? s : 0.2f * s;
                float p = __expf(s - mm) * rl;
                p = ((m1 >> e) & 1u) ? p : 0.f;
                bfr[e] = (short)f2bf(p);
            }
#pragma unroll
            for (int ft = 0; ft < 4; ++ft) {
                const bf16x8 af = *(const bf16x8*)(hp + 32 + ft * 16 * 2048);
                acc[ft] = __builtin_amdgcn_mfma_f32_16x16x32_bf16(af, bfr, acc[ft], 0, 0, 0);
            }
        }
    }
    float* pp = part + (size_t)h * (BB * NN * FO) + (size_t)(b * NN + i) * FO + quad * 4;
#pragma unroll
    for (int ft = 0; ft < 4; ++ft) *(f32x4*)(pp + ft * 16) = acc[ft];
}

// ---------------------------------------------------------------------------
// K6: out = 0.25 * sum_h part[h]
// ---------------------------------------------------------------------------
__global__ __launch_bounds__(256) void k_reduce(const float* __restrict__ part,
                                                float* __restrict__ out) {
    const int idx = blockIdx.x * 256 + threadIdx.x;
    const int M = BB * NN * FO;
    out[idx] = 0.25f * (part[idx] + part[M + idx] + part[2 * M + idx] + part[3 * M + idx]);
}

// ---------------------------------------------------------------------------
// K4 (LAST): alpha write.  Reads the ORIGINAL adj input (16 MB, L3-resident)
// -- NOT adjb, which lives inside the alpha region this kernel overwrites.
// 4 j per thread: int4 adj load + float4 ed loads, 64 contiguous bytes
// stored per thread.  Write-bound (512 MB).
// ---------------------------------------------------------------------------
__global__ __launch_bounds__(256) void k_alpha(const int* __restrict__ adj,
                                               const float* __restrict__ e_src,
                                               const float* __restrict__ e_dst,
                                               const float* __restrict__ mArr,
                                               const float* __restrict__ rlArr,
                                               float* __restrict__ alpha) {
    const int bi = blockIdx.x;
    const int b = bi / NN, i = bi - b * NN;
    const int t = threadIdx.x;
    float ei[HH], mm[HH], rr[HH];
#pragma unroll
    for (int h = 0; h < HH; ++h) {
        ei[h] = e_src[(b * HH + h) * NN + i];
        mm[h] = mArr[(b * HH + h) * NN + i];
        rr[h] = rlArr[(b * HH + h) * NN + i];
    }
    const float* ed = e_dst + b * HH * NN;
    const int* adjrow = adj + (size_t)i * NN;
    float* arow = alpha + (size_t)(b * NN + i) * (NN * HH);
    for (int jq = t; jq < NN / 4; jq += 256) {
        const int j0 = jq * 4;
        const int4 av4 = *(const int4*)(adjrow + j0);
        const int avs[4] = {av4.x, av4.y, av4.z, av4.w};
        float e4[HH * 4];
#pragma unroll
        for (int h = 0; h < HH; ++h) {
            const float4 v = *(const float4*)(ed + h * NN + j0);
            e4[h * 4 + 0] = v.x; e4[h * 4 + 1] = v.y; e4[h * 4 + 2] = v.z; e4[h * 4 + 3] = v.w;
        }
#pragma unroll
        for (int jj = 0; jj < 4; ++jj) {
            const bool av = avs[jj] != 0;
            float o[HH];
#pragma unroll
            for (int h = 0; h < HH; ++h) {
                float s = ei[h] + e4[h * 4 + jj];
                s = s > 0.f ? s : 0.2f * s;
                o[h] = av ? __expf(s - mm[h]) * rr[h] : 0.f;
            }
            float4 ov = {o[0], o[1], o[2], o[3]};
            *(float4*)(arow + (size_t)(j0 + jj) * HH) = ov;
        }
    }
}

// ---------------------------------------------------------------------------
// Launch.  Scratch lives at the start of the alpha output region — dead until
// k_alpha, which runs LAST and reads only input/ws arrays (no scratch!).
//   alpha region layout (floats from alpha base):
//     [0,        4096000)  hfeat
//     [4096000,  8192000)  part
//     [8192000, 10289152)  hT   (bf16, [B][H][64][2048])
//     [10289152, +128000)  adjb (u64,  [2000][32])
// ---------------------------------------------------------------------------
extern "C" void kernel_launch(void* const* d_in, const int* in_sizes, int n_in,
                              void* d_out, int out_size, void* d_ws, size_t ws_size,
                              hipStream_t stream) {
    const float* x  = (const float*)d_in[0];
    const int* adj  = (const int*)d_in[1];
    const float* W  = (const float*)d_in[2];
    const float* a  = (const float*)d_in[3];

    float* out = (float*)d_out;                         // B*N*FO floats
    float* alpha = out + (size_t)BB * NN * FO;          // B*N*N*H floats

    float* hfeat = alpha;
    float* part  = alpha + (size_t)BB * NN * CC;
    unsigned short* hT = (unsigned short*)(alpha + 2 * (size_t)BB * NN * CC);
    u64* adjb = (u64*)(alpha + 2 * (size_t)BB * NN * CC + (size_t)BB * HH * FO * 1024);

    float* ws    = (float*)d_ws;
    float* e_src = ws;
    float* e_dst = e_src + BB * HH * NN;
    float* mArr  = e_dst + BB * HH * NN;
    float* rlArr = mArr + BB * HH * NN;

    k_gemm_xw<<<1000, 256, 0, stream>>>(x, W, hfeat);
    k_adjbits<<<16000, 256, 0, stream>>>(adj, adjb);
    k_calc_e<<<16000, 256, 0, stream>>>(hfeat, a, e_src, e_dst);
    k_softmax_ml<<<16000, 256, 0, stream>>>(adjb, e_src, e_dst, mArr, rlArr);
    k_transpose<<<dim3(32, HH, BB), 256, 0, stream>>>(hfeat, hT);
    k_out_mfma2<<<1000, 256, 0, stream>>>(adjb, hT, e_src, e_dst, mArr, rlArr, part);
    k_reduce<<<4000, 256, 0, stream>>>(part, out);
    k_alpha<<<16000, 256, 0, stream>>>(adj, e_src, e_dst, mArr, rlArr, alpha);  // overwrites scratch
}